// Round 6
// baseline (355.874 us; speedup 1.0000x reference)
//
#include <hip/hip_runtime.h>
#include <math.h>

// ---------------------------------------------------------------------------
// HPFNetCovPool round 6.
// fmt storage: [batch][kt=k/32][row(256)][128B]; 128B = 8x16B slots,
// slot_log = plane*4 + ((k&31)>>3), stored at slot_log ^ (row&7).
// NEW: features are pre-transposed into fmt (transp_k, coalesced+streaming),
// so the conv is a pure fmt x fmt fragment-direct GEMM (no in-loop pack, no
// strided loads). Ft aliases P1..P4 in two 32-batch chunks (ws stays 86 MB).
// NS chain (col_k), meanvar, heads unchanged from round 5.
// ---------------------------------------------------------------------------

typedef __attribute__((ext_vector_type(8))) short bf16x8;
typedef __attribute__((ext_vector_type(4))) float f32x4;
typedef __attribute__((ext_vector_type(4))) unsigned u32x4;
typedef __attribute__((ext_vector_type(2))) unsigned u32x2;

__device__ __forceinline__ unsigned fbits(float f) { union { float f; unsigned u; } x; x.f = f; return x.u; }
__device__ __forceinline__ float bitsf(unsigned u) { union { float f; unsigned u; } x; x.u = u; return x.f; }
__device__ __forceinline__ float bf16v(short h) { return bitsf(((unsigned)(unsigned short)h) << 16); }

__device__ __forceinline__ unsigned pack_h(float a, float b) {
  return (fbits(a) >> 16) | (fbits(b) & 0xFFFF0000u);
}
__device__ __forceinline__ unsigned pack_l(float a, float b) {
  float la = a - bitsf(fbits(a) & 0xFFFF0000u);
  float lb = b - bitsf(fbits(b) & 0xFFFF0000u);
  return (fbits(la) >> 16) | (fbits(lb) & 0xFFFF0000u);
}

// fragment pointer into global fmt
__device__ __forceinline__ const bf16x8* fragp(const char* M, int kt, int row,
                                               int g, int pl) {
  return (const bf16x8*)(M + (size_t)kt * 32768 + (size_t)row * 128 +
                         ((((pl << 2) + g) ^ (row & 7)) << 4));
}
// fragment pointer into LDS P-panel (kt-stride 8 KB: 64 rows x 128B)
__device__ __forceinline__ const bf16x8* fragl(const char* L, int kt, int row,
                                               int g, int pl) {
  return (const bf16x8*)(L + kt * 8192 + row * 128 +
                         ((((pl << 2) + g) ^ (row & 7)) << 4));
}

__device__ __forceinline__ void write_quad_g(char* M, int row, int k0,
                                             const float* v) {
  char* rp = M + (size_t)(k0 >> 5) * 32768 + (size_t)row * 128;
  const int s = (k0 & 31) >> 3, bo = (k0 & 7) * 2;
  *(u32x2*)(rp + (((s) ^ (row & 7)) << 4) + bo) =
      (u32x2){pack_h(v[0], v[1]), pack_h(v[2], v[3])};
  *(u32x2*)(rp + (((s + 4) ^ (row & 7)) << 4) + bo) =
      (u32x2){pack_l(v[0], v[1]), pack_l(v[2], v[3])};
}
__device__ __forceinline__ void write_quad_l(char* L, int row, int k0,
                                             const float* v) {
  char* rp = L + (k0 >> 5) * 8192 + row * 128;
  const int s = (k0 & 31) >> 3, bo = (k0 & 7) * 2;
  *(u32x2*)(rp + (((s) ^ (row & 7)) << 4) + bo) =
      (u32x2){pack_h(v[0], v[1]), pack_h(v[2], v[3])};
  *(u32x2*)(rp + (((s + 4) ^ (row & 7)) << 4) + bo) =
      (u32x2){pack_l(v[0], v[1]), pack_l(v[2], v[3])};
}
__device__ __forceinline__ void read_quad_g(const char* M, int row, int k0,
                                            float* v) {
  const char* rp = M + (size_t)(k0 >> 5) * 32768 + (size_t)row * 128;
  const int s = (k0 & 31) >> 3, bo = (k0 & 7) * 2;
  const u32x2 hq = *(const u32x2*)(rp + (((s) ^ (row & 7)) << 4) + bo);
  const u32x2 lq = *(const u32x2*)(rp + (((s + 4) ^ (row & 7)) << 4) + bo);
  v[0] = bitsf(hq[0] << 16) + bitsf(lq[0] << 16);
  v[1] = bitsf(hq[0] & 0xFFFF0000u) + bitsf(lq[0] & 0xFFFF0000u);
  v[2] = bitsf(hq[1] << 16) + bitsf(lq[1] << 16);
  v[3] = bitsf(hq[1] & 0xFFFF0000u) + bitsf(lq[1] & 0xFFFF0000u);
}

#define MFMA3(c, aH, aL, bH, bL)                                            \
  c = __builtin_amdgcn_mfma_f32_16x16x32_bf16(aL, bH, c, 0, 0, 0);          \
  c = __builtin_amdgcn_mfma_f32_16x16x32_bf16(aH, bL, c, 0, 0, 0);          \
  c = __builtin_amdgcn_mfma_f32_16x16x32_bf16(aH, bH, c, 0, 0, 0);

// ---------------------------------------------------------------------------
// transpose F[b][2048ch][256px] fp32 -> Ft fmt [bl][kt=ch/32][row=px][128B].
// grid (64 kt, 32 bl). Thread px: 32 coalesced dword loads + one 128B row.
__global__ __launch_bounds__(256) void transp_k(const float* __restrict__ F,
                                                char* __restrict__ Ft, int b0)
{
  const int kt = blockIdx.x, bl = blockIdx.y, px = threadIdx.x;
  const float* src = F + ((size_t)(b0 + bl) * 2048 + (size_t)kt * 32) * 256 + px;
  float v[32];
#pragma unroll
  for (int c = 0; c < 32; ++c) v[c] = src[(size_t)c * 256];
  char* rp = Ft + (size_t)bl * 2097152 + (size_t)kt * 32768 + (size_t)px * 128;
#pragma unroll
  for (int s = 0; s < 4; ++s) {
    const float* x = v + s * 8;
    *(u32x4*)(rp + ((s ^ (px & 7)) << 4)) =
        (u32x4){pack_h(x[0], x[1]), pack_h(x[2], x[3]),
                pack_h(x[4], x[5]), pack_h(x[6], x[7])};
    *(u32x4*)(rp + (((s + 4) ^ (px & 7)) << 4)) =
        (u32x4){pack_l(x[0], x[1]), pack_l(x[2], x[3]),
                pack_l(x[4], x[5]), pack_l(x[6], x[7])};
  }
}

// ---------------------------------------------------------------------------
// conv as fmt GEMM: X[ch][px] = Wf @ Ft^T + bias, K=2048.
// grid (4 jb, 4 ib, 32 bl), 256 thr, 4 waves (2x2), tile 64x64, wave 32x32.
__global__ __launch_bounds__(256) void conv2_k(
    const char* __restrict__ Wf, const char* __restrict__ Ft,
    char* __restrict__ X, const float* __restrict__ bias, int b0)
{
  const int tid = threadIdx.x, lane = tid & 63, w = tid >> 6;
  const int wr = w >> 1, wc = w & 1, fr = lane & 15, g = lane >> 4;
  const int bz = b0 + blockIdx.z;
  const char* Fb = Ft + (size_t)blockIdx.z * 2097152;
  const int ib = blockIdx.y * 64, jb = blockIdx.x * 64;

  f32x4 acc[2][2] = {};
  bf16x8 pa[2][2][2], pb[2][2][2];

#pragma unroll
  for (int par = 0; par < 2; ++par) {
#pragma unroll
    for (int m = 0; m < 2; ++m) {
      const int r = ib + wr * 32 + m * 16 + fr;
#pragma unroll
      for (int pl = 0; pl < 2; ++pl) pa[par][m][pl] = *fragp(Wf, par, r, g, pl);
    }
#pragma unroll
    for (int n = 0; n < 2; ++n) {
      const int r = jb + wc * 32 + n * 16 + fr;
#pragma unroll
      for (int pl = 0; pl < 2; ++pl) pb[par][n][pl] = *fragp(Fb, par, r, g, pl);
    }
  }

  for (int t2 = 0; t2 < 64; t2 += 2) {
#pragma unroll
    for (int par = 0; par < 2; ++par) {
      const int t = t2 + par;
      bf16x8 aH[2], aL[2], bH[2], bL[2];
#pragma unroll
      for (int m = 0; m < 2; ++m) { aH[m] = pa[par][m][0]; aL[m] = pa[par][m][1]; }
#pragma unroll
      for (int n = 0; n < 2; ++n) { bH[n] = pb[par][n][0]; bL[n] = pb[par][n][1]; }
      if (t + 2 < 64) {
#pragma unroll
        for (int m = 0; m < 2; ++m) {
          const int r = ib + wr * 32 + m * 16 + fr;
#pragma unroll
          for (int pl = 0; pl < 2; ++pl)
            pa[par][m][pl] = *fragp(Wf, t + 2, r, g, pl);
        }
#pragma unroll
        for (int n = 0; n < 2; ++n) {
          const int r = jb + wc * 32 + n * 16 + fr;
#pragma unroll
          for (int pl = 0; pl < 2; ++pl)
            pb[par][n][pl] = *fragp(Fb, t + 2, r, g, pl);
        }
      }
#pragma unroll
      for (int m = 0; m < 2; ++m)
#pragma unroll
        for (int n = 0; n < 2; ++n) {
          f32x4 c = acc[m][n];
          MFMA3(c, aH[m], aL[m], bH[n], bL[n]);
          acc[m][n] = c;
        }
    }
  }

  // epilogue: X fmt row = channel gi, k = pixel gj (scalar h/l 2B stores)
  char* Xb = X + (size_t)bz * 262144;
#pragma unroll
  for (int m = 0; m < 2; ++m) {
    const int gi0 = ib + wr * 32 + m * 16 + g * 4;
#pragma unroll
    for (int n = 0; n < 2; ++n) {
      const int gj = jb + wc * 32 + n * 16 + fr;
      const int ktj = gj >> 5, sj = (gj & 31) >> 3, bo = (gj & 7) * 2;
#pragma unroll
      for (int j = 0; j < 4; ++j) {
        const int gi = gi0 + j;
        char* rp = Xb + (size_t)ktj * 32768 + (size_t)gi * 128;
        const float v = acc[m][n][j] + bias[gi];
        const unsigned u = fbits(v);
        *(short*)(rp + ((sj ^ (gi & 7)) << 4) + bo) = (short)(u >> 16);
        *(short*)(rp + (((sj + 4) ^ (gi & 7)) << 4) + bo) =
            (short)(fbits(v - bitsf(u & 0xFFFF0000u)) >> 16);
      }
    }
  }
}

// ---------------------------------------------------------------------------
// Column-fused NS kernel (unchanged from round 5).
// MODE 0 COV : s1 out = X@X^T col-panel -> An(outA), Z0(outB)
// MODE 1 Y0  : s1 out = An@An col-panel -> Y0 = 1.5An - 0.5 An^2 (outA)
// MODE 2 IT  : s1 P = Z@Y[:,c] -> LDS; s2 Yn(outA), Zn(outB)
// MODE 3 FIN : s1 P -> LDS; s2 S = (1.5Y - 0.5 Y@P) * sqrt(nrm) -> Sf (fp32)
template <int MODE>
__global__ __launch_bounds__(512) void col_k(
    const char* __restrict__ A1, const char* __restrict__ Bsrc,
    const char* __restrict__ Ys, const char* __restrict__ Zs,
    char* __restrict__ outA, char* __restrict__ outB,
    const float* __restrict__ mu, const float* __restrict__ nrm,
    float* __restrict__ Sf)
{
  __shared__ __align__(16) char Plds[65536];
  const int tid = threadIdx.x, lane = tid & 63, w = tid >> 6;
  const int fr = lane & 15, g = lane >> 4;
  const int blk = blockIdx.x;
  const int bz = (blk & 7) * 8 + ((blk >> 3) & 7);  // XCD batch affinity
  const int jb = (blk >> 6) * 64;
  const size_t MB = 262144;
  const char* Ab = A1 + (size_t)bz * MB;
  const char* Bb = Bsrc + (size_t)bz * MB;
  const int r0 = g * 4;

  f32x4 acc[2][4] = {};
  {
    bf16x8 pa[2][2][2], pb[2][4][2];
#pragma unroll
    for (int par = 0; par < 2; ++par) {
#pragma unroll
      for (int m = 0; m < 2; ++m) {
        const int r = w * 32 + m * 16 + fr;
#pragma unroll
        for (int pl = 0; pl < 2; ++pl) pa[par][m][pl] = *fragp(Ab, par, r, g, pl);
      }
#pragma unroll
      for (int n = 0; n < 4; ++n) {
        const int r = jb + n * 16 + fr;
#pragma unroll
        for (int pl = 0; pl < 2; ++pl) pb[par][n][pl] = *fragp(Bb, par, r, g, pl);
      }
    }
    for (int t2 = 0; t2 < 8; t2 += 2) {
#pragma unroll
      for (int par = 0; par < 2; ++par) {
        const int t = t2 + par;
        bf16x8 aH[2], aL[2], bH[4], bL[4];
#pragma unroll
        for (int m = 0; m < 2; ++m) { aH[m] = pa[par][m][0]; aL[m] = pa[par][m][1]; }
#pragma unroll
        for (int n = 0; n < 4; ++n) { bH[n] = pb[par][n][0]; bL[n] = pb[par][n][1]; }
        if (t + 2 < 8) {
#pragma unroll
          for (int m = 0; m < 2; ++m) {
            const int r = w * 32 + m * 16 + fr;
#pragma unroll
            for (int pl = 0; pl < 2; ++pl)
              pa[par][m][pl] = *fragp(Ab, t + 2, r, g, pl);
          }
#pragma unroll
          for (int n = 0; n < 4; ++n) {
            const int r = jb + n * 16 + fr;
#pragma unroll
            for (int pl = 0; pl < 2; ++pl)
              pb[par][n][pl] = *fragp(Bb, t + 2, r, g, pl);
          }
        }
#pragma unroll
        for (int m = 0; m < 2; ++m)
#pragma unroll
          for (int n = 0; n < 4; ++n) {
            f32x4 c = acc[m][n];
            MFMA3(c, aH[m], aL[m], bH[n], bL[n]);
            acc[m][n] = c;
          }
      }
    }
  }

  if constexpr (MODE == 0) {
    const float rn = 1.0f / nrm[bz];
    const float* mub = mu + bz * 256;
    char* oA = outA + (size_t)bz * MB;
    char* oB = outB + (size_t)bz * MB;
#pragma unroll
    for (int m = 0; m < 2; ++m) {
      const int gi0 = w * 32 + m * 16 + r0;
#pragma unroll
      for (int n = 0; n < 4; ++n) {
        const int gj = jb + n * 16 + fr;
        float vv[4], zz[4];
#pragma unroll
        for (int j = 0; j < 4; ++j) {
          const float v =
              (acc[m][n][j] * (1.f / 256.f) - mub[gi0 + j] * mub[gj]) * rn;
          vv[j] = v;
          zz[j] = (gi0 + j == gj ? 1.5f : 0.f) - 0.5f * v;
        }
        write_quad_g(oA, gj, gi0, vv);
        write_quad_g(oB, gj, gi0, zz);
      }
    }
  } else if constexpr (MODE == 1) {
    char* oA = outA + (size_t)bz * MB;
#pragma unroll
    for (int m = 0; m < 2; ++m) {
      const int gi0 = w * 32 + m * 16 + r0;
#pragma unroll
      for (int n = 0; n < 4; ++n) {
        const int gj = jb + n * 16 + fr;
        float av[4], vv[4];
        read_quad_g(Bb, gj, gi0, av);
#pragma unroll
        for (int j = 0; j < 4; ++j) vv[j] = 1.5f * av[j] - 0.5f * acc[m][n][j];
        write_quad_g(oA, gj, gi0, vv);
      }
    }
  } else {
#pragma unroll
    for (int m = 0; m < 2; ++m) {
      const int gi0 = w * 32 + m * 16 + r0;
#pragma unroll
      for (int n = 0; n < 4; ++n) {
        const int jl = n * 16 + fr;
        float vv[4] = {acc[m][n][0], acc[m][n][1], acc[m][n][2], acc[m][n][3]};
        write_quad_l(Plds, jl, gi0, vv);
      }
    }
    __syncthreads();

    const char* Yb = Ys + (size_t)bz * MB;
    const char* Zb = (MODE == 2) ? (Zs + (size_t)bz * MB) : nullptr;
    f32x4 aY[2][4] = {}, aZ[2][4] = {};
    bf16x8 py[2][2][2], pz[2][2][2];
#pragma unroll
    for (int par = 0; par < 2; ++par)
#pragma unroll
      for (int m = 0; m < 2; ++m) {
        const int r = w * 32 + m * 16 + fr;
#pragma unroll
        for (int pl = 0; pl < 2; ++pl) {
          py[par][m][pl] = *fragp(Yb, par, r, g, pl);
          if constexpr (MODE == 2) pz[par][m][pl] = *fragp(Zb, par, r, g, pl);
        }
      }
    for (int t2 = 0; t2 < 8; t2 += 2) {
#pragma unroll
      for (int par = 0; par < 2; ++par) {
        const int t = t2 + par;
        bf16x8 yH[2], yL[2], zH[2], zL[2];
#pragma unroll
        for (int m = 0; m < 2; ++m) {
          yH[m] = py[par][m][0]; yL[m] = py[par][m][1];
          if constexpr (MODE == 2) { zH[m] = pz[par][m][0]; zL[m] = pz[par][m][1]; }
        }
        if (t + 2 < 8) {
#pragma unroll
          for (int m = 0; m < 2; ++m) {
            const int r = w * 32 + m * 16 + fr;
#pragma unroll
            for (int pl = 0; pl < 2; ++pl) {
              py[par][m][pl] = *fragp(Yb, t + 2, r, g, pl);
              if constexpr (MODE == 2) pz[par][m][pl] = *fragp(Zb, t + 2, r, g, pl);
            }
          }
        }
        bf16x8 bH[4], bL[4];
#pragma unroll
        for (int n = 0; n < 4; ++n) {
          const int jl = n * 16 + fr;
          bH[n] = *fragl(Plds, t, jl, g, 0);
          bL[n] = *fragl(Plds, t, jl, g, 1);
        }
#pragma unroll
        for (int m = 0; m < 2; ++m)
#pragma unroll
          for (int n = 0; n < 4; ++n) {
            f32x4 cy = aY[m][n];
            MFMA3(cy, yH[m], yL[m], bH[n], bL[n]);
            aY[m][n] = cy;
            if constexpr (MODE == 2) {
              f32x4 cz = aZ[m][n];
              MFMA3(cz, zH[m], zL[m], bH[n], bL[n]);
              aZ[m][n] = cz;
            }
          }
      }
    }
    if constexpr (MODE == 2) {
      char* oA = outA + (size_t)bz * MB;
      char* oB = outB + (size_t)bz * MB;
#pragma unroll
      for (int m = 0; m < 2; ++m) {
        const int gi0 = w * 32 + m * 16 + r0;
#pragma unroll
        for (int n = 0; n < 4; ++n) {
          const int gj = jb + n * 16 + fr;
          float base[4], vv[4];
          read_quad_g(Yb, gj, gi0, base);
#pragma unroll
          for (int j = 0; j < 4; ++j) vv[j] = 1.5f * base[j] - 0.5f * aY[m][n][j];
          write_quad_g(oA, gj, gi0, vv);
          read_quad_g(Zb, gj, gi0, base);
#pragma unroll
          for (int j = 0; j < 4; ++j) vv[j] = 1.5f * base[j] - 0.5f * aZ[m][n][j];
          write_quad_g(oB, gj, gi0, vv);
        }
      }
    } else {
      const float sq = sqrtf(nrm[bz]);
      float* Sb = Sf + (size_t)bz * 65536;
#pragma unroll
      for (int m = 0; m < 2; ++m) {
        const int gi0 = w * 32 + m * 16 + r0;
#pragma unroll
        for (int n = 0; n < 4; ++n) {
          const int gj = jb + n * 16 + fr;
          float base[4];
          read_quad_g(Yb, gj, gi0, base);
          f32x4 vv;
#pragma unroll
          for (int j = 0; j < 4; ++j)
            vv[j] = (1.5f * base[j] - 0.5f * aY[m][n][j]) * sq;
          *(f32x4*)(Sb + (size_t)gj * 256 + gi0) = vv;
        }
      }
    }
  }
}

// ---------------------------------------------------------------------------
// w_bn [256][2048] fp32 -> fmt.
__global__ __launch_bounds__(256) void cvt_w(const float* __restrict__ wsrc,
                                             char* __restrict__ Wf)
{
  const int kt = blockIdx.x, r = threadIdx.x;
  const float* src = wsrc + (size_t)r * 2048 + kt * 32;
  char* rp = Wf + (size_t)kt * 32768 + (size_t)r * 128;
#pragma unroll
  for (int s = 0; s < 4; ++s) {
    float x[8];
#pragma unroll
    for (int e = 0; e < 8; ++e) x[e] = src[s * 8 + e];
    *(u32x4*)(rp + ((s ^ (r & 7)) << 4)) =
        (u32x4){pack_h(x[0], x[1]), pack_h(x[2], x[3]), pack_h(x[4], x[5]), pack_h(x[6], x[7])};
    *(u32x4*)(rp + (((s + 4) ^ (r & 7)) << 4)) =
        (u32x4){pack_l(x[0], x[1]), pack_l(x[2], x[3]), pack_l(x[4], x[5]), pack_l(x[6], x[7])};
  }
}

// ---------------------------------------------------------------------------
// W2[v][i*256+j] = w[v][tri(min,max)] * (i==j ? 1 : 0.5)
__global__ __launch_bounds__(256) void build_w2(const float* __restrict__ w_type,
                                                const float* __restrict__ w_flag,
                                                float* __restrict__ W2)
{
  const int v = blockIdx.x >> 6, chunk = blockIdx.x & 63;
  const float* src = (v < 4) ? (w_type + (size_t)v * 32896) : w_flag;
  const int e0 = chunk * 1024 + threadIdx.x * 4;
#pragma unroll
  for (int q = 0; q < 4; ++q) {
    const int e = e0 + q;
    const int i = e >> 8, j = e & 255;
    const int r = i < j ? i : j, c = i < j ? j : i;
    const int t = r * 256 - (r * (r - 1)) / 2 + (c - r);
    W2[(size_t)v * 65536 + e] = src[t] * (i == j ? 1.0f : 0.5f);
  }
}

// ---------------------------------------------------------------------------
// Per-row mean + trace(cov), from X in fmt.
__global__ __launch_bounds__(256) void meanvar(const char* __restrict__ X,
                                               float* __restrict__ mu,
                                               float* __restrict__ nrm)
{
  const int b = blockIdx.x, i = threadIdx.x;
  const char* rp0 = X + (size_t)b * 262144 + (size_t)i * 128;
  float s = 0.f, ss = 0.f;
  for (int kt = 0; kt < 8; ++kt) {
    const char* rp = rp0 + kt * 32768;
#pragma unroll
    for (int sl = 0; sl < 4; ++sl) {
      bf16x8 h8 = *(const bf16x8*)(rp + ((sl ^ (i & 7)) << 4));
      bf16x8 l8 = *(const bf16x8*)(rp + (((sl + 4) ^ (i & 7)) << 4));
#pragma unroll
      for (int e = 0; e < 8; ++e) {
        const float v = bf16v(h8[e]) + bf16v(l8[e]);
        s += v; ss += v * v;
      }
    }
  }
  const float m = s * (1.f / 256.f);
  mu[b * 256 + i] = m;
  __shared__ float red[256];
  red[i] = ss * (1.f / 256.f) - m * m;
  __syncthreads();
  for (int o = 128; o > 0; o >>= 1) {
    if (i < o) red[i] += red[i + o];
    __syncthreads();
  }
  if (i == 0) nrm[b] = red[0];
}

// ---------------------------------------------------------------------------
// Heads: out[b,v] = dot(S_b, W2_v) + bias.
__global__ __launch_bounds__(256) void head2(
    const float* __restrict__ Sf, const float* __restrict__ W2,
    const float* __restrict__ b_type, const float* __restrict__ b_flag,
    float* __restrict__ out)
{
  const int b = blockIdx.x, v = blockIdx.y, tid = threadIdx.x;
  const float4* s4 = (const float4*)(Sf + (size_t)b * 65536);
  const float4* w4 = (const float4*)(W2 + (size_t)v * 65536);
  float acc = 0.f;
  for (int i = tid; i < 16384; i += 256) {
    const float4 a = s4[i], c = w4[i];
    acc += a.x * c.x + a.y * c.y + a.z * c.z + a.w * c.w;
  }
  __shared__ float red[256];
  red[tid] = acc;
  __syncthreads();
  for (int o = 128; o > 0; o >>= 1) {
    if (tid < o) red[tid] += red[tid + o];
    __syncthreads();
  }
  if (tid == 0) {
    if (v < 4) out[b * 4 + v] = red[0] + b_type[v];
    else       out[256 + b] = red[0] + b_flag[0];
  }
}

// ---------------------------------------------------------------------------
extern "C" void kernel_launch(void* const* d_in, const int* in_sizes, int n_in,
                              void* d_out, int out_size, void* d_ws, size_t ws_size,
                              hipStream_t stream)
{
  const float* features = (const float*)d_in[0];
  const float* w_bn     = (const float*)d_in[1];
  const float* b_bn     = (const float*)d_in[2];
  const float* w_type   = (const float*)d_in[3];
  const float* b_type   = (const float*)d_in[4];
  const float* w_flag   = (const float*)d_in[5];
  const float* b_flag   = (const float*)d_in[6];
  float* out = (float*)d_out;

  char* W = (char*)d_ws;
  const size_t PB = 16777216;
  char* P0 = W;           char* P1 = W + PB;     char* P2 = W + 2 * PB;
  char* P3 = W + 3 * PB;  char* P4 = W + 4 * PB;
  char* Wf = W + 5 * PB;            // 2 MB; dead after conv -> W2 aliases it
  float* W2 = (float*)Wf;
  float* mu = (float*)(W + 5 * PB + 2097152);
  float* nrm = mu + 64 * 256;
  float* Sf = (float*)P4;           // final S fp32 (P4 dead by then)
  char* Ft = P1;                    // 64 MB transposed-features chunk (P1..P4)

  cvt_w<<<dim3(64), dim3(256), 0, stream>>>(w_bn, Wf);
  // chunk 1: batches 0..31
  transp_k<<<dim3(64, 32), dim3(256), 0, stream>>>(features, Ft, 0);
  conv2_k<<<dim3(4, 4, 32), dim3(256), 0, stream>>>(Wf, Ft, P0, b_bn, 0);
  // chunk 2: batches 32..63
  transp_k<<<dim3(64, 32), dim3(256), 0, stream>>>(features, Ft, 32);
  conv2_k<<<dim3(4, 4, 32), dim3(256), 0, stream>>>(Wf, Ft, P0, b_bn, 32);

  build_w2<<<dim3(320), dim3(256), 0, stream>>>(w_type, w_flag, W2);
  meanvar<<<dim3(64), dim3(256), 0, stream>>>(P0, mu, nrm);

  const dim3 cg(256), cb(512);
  // cov: An(P1), Z0(P2)
  col_k<0><<<cg, cb, 0, stream>>>(P0, P0, nullptr, nullptr, P1, P2, mu, nrm, nullptr);
  // Y0(P3) = 1.5An - 0.5 An^2
  col_k<1><<<cg, cb, 0, stream>>>(P1, P1, nullptr, nullptr, P3, nullptr, nullptr, nullptr, nullptr);
  // it1: Z=P2, Y=P3 -> Yn P0, Zn P4
  col_k<2><<<cg, cb, 0, stream>>>(P2, P3, P3, P2, P0, P4, nullptr, nullptr, nullptr);
  // it2: Z=P4, Y=P0 -> Yn P1, Zn P2
  col_k<2><<<cg, cb, 0, stream>>>(P4, P0, P0, P4, P1, P2, nullptr, nullptr, nullptr);
  // it3: Z=P2, Y=P1 -> Yn P3, Zn P0
  col_k<2><<<cg, cb, 0, stream>>>(P2, P1, P1, P2, P3, P0, nullptr, nullptr, nullptr);
  // fin: Z=P0, Y=P3 -> Sf
  col_k<3><<<cg, cb, 0, stream>>>(P0, P3, P3, nullptr, nullptr, nullptr, nullptr, nrm, Sf);

  head2<<<dim3(64, 5), dim3(256), 0, stream>>>(Sf, W2, b_type, b_flag, out);
  (void)in_sizes; (void)n_in; (void)out_size; (void)ws_size;
}

// Round 7
// 344.709 us; speedup vs baseline: 1.0324x; 1.0324x over previous
//
#include <hip/hip_runtime.h>
#include <math.h>

// ---------------------------------------------------------------------------
// HPFNetCovPool round 7.
// fmt storage: [batch][kt=k/32][row(256)][128B]; 128B = 8x16B slots,
// slot_log = plane*4 + ((k&31)>>3), stored at slot_log ^ (row&7).
//  - prep_k: ONE dispatch = transpose F->Ft(fmt, full 128 MB) + cvt_w + build_w2
//  - conv3_k: LDS-staged fmt GEMM, tile 128x64, 3-buf counted-vmcnt (all loop
//    VMEM = global_load_lds so vmcnt counting is exact), 1 barrier/kt.
//  - col_k NS chain: fragment-direct from L2 (XCD batch affinity), stage2
//    Y/Z prefetch hoisted above the P-panel sync.
// ws budget ~537 MB (fillBuffer evidence); we use ~217 MB.
// ---------------------------------------------------------------------------

typedef __attribute__((ext_vector_type(8))) short bf16x8;
typedef __attribute__((ext_vector_type(4))) float f32x4;
typedef __attribute__((ext_vector_type(4))) unsigned u32x4;
typedef __attribute__((ext_vector_type(2))) unsigned u32x2;

__device__ __forceinline__ unsigned fbits(float f) { union { float f; unsigned u; } x; x.f = f; return x.u; }
__device__ __forceinline__ float bitsf(unsigned u) { union { float f; unsigned u; } x; x.u = u; return x.f; }
__device__ __forceinline__ float bf16v(short h) { return bitsf(((unsigned)(unsigned short)h) << 16); }

__device__ __forceinline__ unsigned pack_h(float a, float b) {
  return (fbits(a) >> 16) | (fbits(b) & 0xFFFF0000u);
}
__device__ __forceinline__ unsigned pack_l(float a, float b) {
  float la = a - bitsf(fbits(a) & 0xFFFF0000u);
  float lb = b - bitsf(fbits(b) & 0xFFFF0000u);
  return (fbits(la) >> 16) | (fbits(lb) & 0xFFFF0000u);
}

__device__ __forceinline__ const bf16x8* fragp(const char* M, int kt, int row,
                                               int g, int pl) {
  return (const bf16x8*)(M + (size_t)kt * 32768 + (size_t)row * 128 +
                         ((((pl << 2) + g) ^ (row & 7)) << 4));
}
__device__ __forceinline__ const bf16x8* fragl(const char* L, int kt, int row,
                                               int g, int pl) {
  return (const bf16x8*)(L + kt * 8192 + row * 128 +
                         ((((pl << 2) + g) ^ (row & 7)) << 4));
}

__device__ __forceinline__ void write_quad_g(char* M, int row, int k0,
                                             const float* v) {
  char* rp = M + (size_t)(k0 >> 5) * 32768 + (size_t)row * 128;
  const int s = (k0 & 31) >> 3, bo = (k0 & 7) * 2;
  *(u32x2*)(rp + (((s) ^ (row & 7)) << 4) + bo) =
      (u32x2){pack_h(v[0], v[1]), pack_h(v[2], v[3])};
  *(u32x2*)(rp + (((s + 4) ^ (row & 7)) << 4) + bo) =
      (u32x2){pack_l(v[0], v[1]), pack_l(v[2], v[3])};
}
__device__ __forceinline__ void write_quad_l(char* L, int row, int k0,
                                             const float* v) {
  char* rp = L + (k0 >> 5) * 8192 + row * 128;
  const int s = (k0 & 31) >> 3, bo = (k0 & 7) * 2;
  *(u32x2*)(rp + (((s) ^ (row & 7)) << 4) + bo) =
      (u32x2){pack_h(v[0], v[1]), pack_h(v[2], v[3])};
  *(u32x2*)(rp + (((s + 4) ^ (row & 7)) << 4) + bo) =
      (u32x2){pack_l(v[0], v[1]), pack_l(v[2], v[3])};
}
__device__ __forceinline__ void read_quad_g(const char* M, int row, int k0,
                                            float* v) {
  const char* rp = M + (size_t)(k0 >> 5) * 32768 + (size_t)row * 128;
  const int s = (k0 & 31) >> 3, bo = (k0 & 7) * 2;
  const u32x2 hq = *(const u32x2*)(rp + (((s) ^ (row & 7)) << 4) + bo);
  const u32x2 lq = *(const u32x2*)(rp + (((s + 4) ^ (row & 7)) << 4) + bo);
  v[0] = bitsf(hq[0] << 16) + bitsf(lq[0] << 16);
  v[1] = bitsf(hq[0] & 0xFFFF0000u) + bitsf(lq[0] & 0xFFFF0000u);
  v[2] = bitsf(hq[1] << 16) + bitsf(lq[1] << 16);
  v[3] = bitsf(hq[1] & 0xFFFF0000u) + bitsf(lq[1] & 0xFFFF0000u);
}

__device__ __forceinline__ void gld16(const void* g, void* l) {
  __builtin_amdgcn_global_load_lds(
      (const __attribute__((address_space(1))) void*)(size_t)(g),
      (__attribute__((address_space(3))) void*)(unsigned)(size_t)(l), 16, 0, 0);
}

#define WAIT_VM(N) asm volatile("s_waitcnt vmcnt(" #N ")" ::: "memory")
#define BARRIER() do { __builtin_amdgcn_s_barrier(); asm volatile("" ::: "memory"); } while (0)

#define MFMA3(c, aH, aL, bH, bL)                                            \
  c = __builtin_amdgcn_mfma_f32_16x16x32_bf16(aL, bH, c, 0, 0, 0);          \
  c = __builtin_amdgcn_mfma_f32_16x16x32_bf16(aH, bL, c, 0, 0, 0);          \
  c = __builtin_amdgcn_mfma_f32_16x16x32_bf16(aH, bH, c, 0, 0, 0);

// ---------------------------------------------------------------------------
// prep: [0,4096) transpose F->Ft ; [4096,4160) w_bn->Wf ; [4160,4480) W2.
__global__ __launch_bounds__(256) void prep_k(
    const float* __restrict__ F, const float* __restrict__ w_bn,
    const float* __restrict__ w_type, const float* __restrict__ w_flag,
    char* __restrict__ Ft, char* __restrict__ Wf, float* __restrict__ W2)
{
  const int bid = blockIdx.x;
  if (bid < 4096) {
    const int kt = bid & 63, bl = bid >> 6, px = threadIdx.x;
    const float* src = F + ((size_t)bl * 2048 + (size_t)kt * 32) * 256 + px;
    float v[32];
#pragma unroll
    for (int c = 0; c < 32; ++c) v[c] = src[(size_t)c * 256];
    char* rp = Ft + (size_t)bl * 2097152 + (size_t)kt * 32768 + (size_t)px * 128;
#pragma unroll
    for (int s = 0; s < 4; ++s) {
      const float* x = v + s * 8;
      *(u32x4*)(rp + ((s ^ (px & 7)) << 4)) =
          (u32x4){pack_h(x[0], x[1]), pack_h(x[2], x[3]),
                  pack_h(x[4], x[5]), pack_h(x[6], x[7])};
      *(u32x4*)(rp + (((s + 4) ^ (px & 7)) << 4)) =
          (u32x4){pack_l(x[0], x[1]), pack_l(x[2], x[3]),
                  pack_l(x[4], x[5]), pack_l(x[6], x[7])};
    }
  } else if (bid < 4160) {
    const int kt = bid - 4096, r = threadIdx.x;
    const float* src = w_bn + (size_t)r * 2048 + kt * 32;
    char* rp = Wf + (size_t)kt * 32768 + (size_t)r * 128;
#pragma unroll
    for (int s = 0; s < 4; ++s) {
      float x[8];
#pragma unroll
      for (int e = 0; e < 8; ++e) x[e] = src[s * 8 + e];
      *(u32x4*)(rp + ((s ^ (r & 7)) << 4)) =
          (u32x4){pack_h(x[0], x[1]), pack_h(x[2], x[3]),
                  pack_h(x[4], x[5]), pack_h(x[6], x[7])};
      *(u32x4*)(rp + (((s + 4) ^ (r & 7)) << 4)) =
          (u32x4){pack_l(x[0], x[1]), pack_l(x[2], x[3]),
                  pack_l(x[4], x[5]), pack_l(x[6], x[7])};
    }
  } else {
    const int idx = bid - 4160;
    const int v = idx >> 6, chunk = idx & 63;
    const float* src = (v < 4) ? (w_type + (size_t)v * 32896) : w_flag;
    const int e0 = chunk * 1024 + threadIdx.x * 4;
#pragma unroll
    for (int q = 0; q < 4; ++q) {
      const int e = e0 + q;
      const int i = e >> 8, j = e & 255;
      const int r = i < j ? i : j, c = i < j ? j : i;
      const int t = r * 256 - (r * (r - 1)) / 2 + (c - r);
      W2[(size_t)v * 65536 + e] = src[t] * (i == j ? 1.0f : 0.5f);
    }
  }
}

// ---------------------------------------------------------------------------
// conv: X[ch][px] = Wf @ Ft^T + bias, K=2048. Tile 128ch x 64px, 256 thr
// (4 waves 2x2, wave 64x32). LDS 3-buf x 24KB; per kt: 6 gld16/wave,
// WAIT_VM(12) steady (2 future stages x 6), single barrier. grid (4,2,64).
__global__ __launch_bounds__(256) void conv3_k(
    const char* __restrict__ Wf, const char* __restrict__ Ft,
    char* __restrict__ X, const float* __restrict__ bias)
{
  __shared__ __align__(16) char lds[3 * 24576];
  const int tid = threadIdx.x, lane = tid & 63, w = tid >> 6;
  const int wr = w >> 1, wc = w & 1, fr = lane & 15, g = lane >> 4;
  const int bz = blockIdx.z, ib = blockIdx.y * 128, jb = blockIdx.x * 64;
  const char* Fb = Ft + (size_t)bz * 2097152;

  f32x4 acc[4][2] = {};

  auto stage = [&](int t) {
    char* L = lds + (t % 3) * 24576;
    const char* Ag = Wf + (size_t)t * 32768 + (size_t)ib * 128;
    const char* Bg = Fb + (size_t)t * 32768 + (size_t)jb * 128;
#pragma unroll
    for (int i = 0; i < 6; ++i) {
      const int c = w + i * 4;  // 0..23: 16 A-chunks then 8 B-chunks
      if (c < 16) gld16(Ag + c * 1024 + lane * 16, L + c * 1024);
      else        gld16(Bg + (c - 16) * 1024 + lane * 16, L + 16384 + (c - 16) * 1024);
    }
  };

  stage(0); stage(1);
  for (int t = 0; t < 64; ++t) {
    if (t < 62)      { WAIT_VM(12); }
    else if (t == 62){ WAIT_VM(6); }
    else             { WAIT_VM(0); }
    BARRIER();
    if (t + 2 < 64) stage(t + 2);
    const char* L = lds + (t % 3) * 24576;
    bf16x8 aH[4], aL[4], bH[2], bL[2];
#pragma unroll
    for (int m = 0; m < 4; ++m) {
      const int r = wr * 64 + m * 16 + fr;
      const char* p = L + r * 128;
      aH[m] = *(const bf16x8*)(p + ((g ^ (r & 7)) << 4));
      aL[m] = *(const bf16x8*)(p + (((g + 4) ^ (r & 7)) << 4));
    }
#pragma unroll
    for (int n = 0; n < 2; ++n) {
      const int r = wc * 32 + n * 16 + fr;
      const char* p = L + 16384 + r * 128;
      bH[n] = *(const bf16x8*)(p + ((g ^ (r & 7)) << 4));
      bL[n] = *(const bf16x8*)(p + (((g + 4) ^ (r & 7)) << 4));
    }
#pragma unroll
    for (int m = 0; m < 4; ++m)
#pragma unroll
      for (int n = 0; n < 2; ++n) {
        f32x4 c = acc[m][n];
        MFMA3(c, aH[m], aL[m], bH[n], bL[n]);
        acc[m][n] = c;
      }
  }

  // epilogue: X fmt row = channel gi, k = pixel gj
  char* Xb = X + (size_t)bz * 262144;
#pragma unroll
  for (int m = 0; m < 4; ++m) {
    const int gi0 = ib + wr * 64 + m * 16 + g * 4;
#pragma unroll
    for (int n = 0; n < 2; ++n) {
      const int gj = jb + wc * 32 + n * 16 + fr;
      const int ktj = gj >> 5, sj = (gj & 31) >> 3, bo = (gj & 7) * 2;
#pragma unroll
      for (int j = 0; j < 4; ++j) {
        const int gi = gi0 + j;
        char* rp = Xb + (size_t)ktj * 32768 + (size_t)gi * 128;
        const float v = acc[m][n][j] + bias[gi];
        const unsigned u = fbits(v);
        *(short*)(rp + ((sj ^ (gi & 7)) << 4) + bo) = (short)(u >> 16);
        *(short*)(rp + (((sj + 4) ^ (gi & 7)) << 4) + bo) =
            (short)(fbits(v - bitsf(u & 0xFFFF0000u)) >> 16);
      }
    }
  }
}

// ---------------------------------------------------------------------------
// Column-fused NS kernel. grid 256 x 512 thr (8 waves, rows 32/wave).
template <int MODE>
__global__ __launch_bounds__(512) void col_k(
    const char* __restrict__ A1, const char* __restrict__ Bsrc,
    const char* __restrict__ Ys, const char* __restrict__ Zs,
    char* __restrict__ outA, char* __restrict__ outB,
    const float* __restrict__ mu, const float* __restrict__ nrm,
    float* __restrict__ Sf)
{
  __shared__ __align__(16) char Plds[65536];
  const int tid = threadIdx.x, lane = tid & 63, w = tid >> 6;
  const int fr = lane & 15, g = lane >> 4;
  const int blk = blockIdx.x;
  const int bz = (blk & 7) * 8 + ((blk >> 3) & 7);  // XCD batch affinity
  const int jb = (blk >> 6) * 64;
  const size_t MB = 262144;
  const char* Ab = A1 + (size_t)bz * MB;
  const char* Bb = Bsrc + (size_t)bz * MB;
  const int r0 = g * 4;

  f32x4 acc[2][4] = {};
  {
    bf16x8 pa[2][2][2], pb[2][4][2];
#pragma unroll
    for (int par = 0; par < 2; ++par) {
#pragma unroll
      for (int m = 0; m < 2; ++m) {
        const int r = w * 32 + m * 16 + fr;
#pragma unroll
        for (int pl = 0; pl < 2; ++pl) pa[par][m][pl] = *fragp(Ab, par, r, g, pl);
      }
#pragma unroll
      for (int n = 0; n < 4; ++n) {
        const int r = jb + n * 16 + fr;
#pragma unroll
        for (int pl = 0; pl < 2; ++pl) pb[par][n][pl] = *fragp(Bb, par, r, g, pl);
      }
    }
    for (int t2 = 0; t2 < 8; t2 += 2) {
#pragma unroll
      for (int par = 0; par < 2; ++par) {
        const int t = t2 + par;
        bf16x8 aH[2], aL[2], bH[4], bL[4];
#pragma unroll
        for (int m = 0; m < 2; ++m) { aH[m] = pa[par][m][0]; aL[m] = pa[par][m][1]; }
#pragma unroll
        for (int n = 0; n < 4; ++n) { bH[n] = pb[par][n][0]; bL[n] = pb[par][n][1]; }
        if (t + 2 < 8) {
#pragma unroll
          for (int m = 0; m < 2; ++m) {
            const int r = w * 32 + m * 16 + fr;
#pragma unroll
            for (int pl = 0; pl < 2; ++pl)
              pa[par][m][pl] = *fragp(Ab, t + 2, r, g, pl);
          }
#pragma unroll
          for (int n = 0; n < 4; ++n) {
            const int r = jb + n * 16 + fr;
#pragma unroll
            for (int pl = 0; pl < 2; ++pl)
              pb[par][n][pl] = *fragp(Bb, t + 2, r, g, pl);
          }
        }
#pragma unroll
        for (int m = 0; m < 2; ++m)
#pragma unroll
          for (int n = 0; n < 4; ++n) {
            f32x4 c = acc[m][n];
            MFMA3(c, aH[m], aL[m], bH[n], bL[n]);
            acc[m][n] = c;
          }
      }
    }
  }

  if constexpr (MODE == 0) {
    const float rn = 1.0f / nrm[bz];
    const float* mub = mu + bz * 256;
    char* oA = outA + (size_t)bz * MB;
    char* oB = outB + (size_t)bz * MB;
#pragma unroll
    for (int m = 0; m < 2; ++m) {
      const int gi0 = w * 32 + m * 16 + r0;
#pragma unroll
      for (int n = 0; n < 4; ++n) {
        const int gj = jb + n * 16 + fr;
        float vv[4], zz[4];
#pragma unroll
        for (int j = 0; j < 4; ++j) {
          const float v =
              (acc[m][n][j] * (1.f / 256.f) - mub[gi0 + j] * mub[gj]) * rn;
          vv[j] = v;
          zz[j] = (gi0 + j == gj ? 1.5f : 0.f) - 0.5f * v;
        }
        write_quad_g(oA, gj, gi0, vv);
        write_quad_g(oB, gj, gi0, zz);
      }
    }
  } else if constexpr (MODE == 1) {
    char* oA = outA + (size_t)bz * MB;
#pragma unroll
    for (int m = 0; m < 2; ++m) {
      const int gi0 = w * 32 + m * 16 + r0;
#pragma unroll
      for (int n = 0; n < 4; ++n) {
        const int gj = jb + n * 16 + fr;
        float av[4], vv[4];
        read_quad_g(Bb, gj, gi0, av);
#pragma unroll
        for (int j = 0; j < 4; ++j) vv[j] = 1.5f * av[j] - 0.5f * acc[m][n][j];
        write_quad_g(oA, gj, gi0, vv);
      }
    }
  } else {
    // pack P^T panel into LDS fmt
#pragma unroll
    for (int m = 0; m < 2; ++m) {
      const int gi0 = w * 32 + m * 16 + r0;
#pragma unroll
      for (int n = 0; n < 4; ++n) {
        const int jl = n * 16 + fr;
        float vv[4] = {acc[m][n][0], acc[m][n][1], acc[m][n][2], acc[m][n][3]};
        write_quad_l(Plds, jl, gi0, vv);
      }
    }
    // stage2 Y/Z initial prefetch hoisted ABOVE the sync (hides L2 latency)
    const char* Yb = Ys + (size_t)bz * MB;
    const char* Zb = (MODE == 2) ? (Zs + (size_t)bz * MB) : nullptr;
    bf16x8 py[2][2][2], pz[2][2][2];
#pragma unroll
    for (int par = 0; par < 2; ++par)
#pragma unroll
      for (int m = 0; m < 2; ++m) {
        const int r = w * 32 + m * 16 + fr;
#pragma unroll
        for (int pl = 0; pl < 2; ++pl) {
          py[par][m][pl] = *fragp(Yb, par, r, g, pl);
          if constexpr (MODE == 2) pz[par][m][pl] = *fragp(Zb, par, r, g, pl);
        }
      }
    __syncthreads();

    f32x4 aY[2][4] = {}, aZ[2][4] = {};
    for (int t2 = 0; t2 < 8; t2 += 2) {
#pragma unroll
      for (int par = 0; par < 2; ++par) {
        const int t = t2 + par;
        bf16x8 yH[2], yL[2], zH[2], zL[2];
#pragma unroll
        for (int m = 0; m < 2; ++m) {
          yH[m] = py[par][m][0]; yL[m] = py[par][m][1];
          if constexpr (MODE == 2) { zH[m] = pz[par][m][0]; zL[m] = pz[par][m][1]; }
        }
        if (t + 2 < 8) {
#pragma unroll
          for (int m = 0; m < 2; ++m) {
            const int r = w * 32 + m * 16 + fr;
#pragma unroll
            for (int pl = 0; pl < 2; ++pl) {
              py[par][m][pl] = *fragp(Yb, t + 2, r, g, pl);
              if constexpr (MODE == 2) pz[par][m][pl] = *fragp(Zb, t + 2, r, g, pl);
            }
          }
        }
        bf16x8 bH[4], bL[4];
#pragma unroll
        for (int n = 0; n < 4; ++n) {
          const int jl = n * 16 + fr;
          bH[n] = *fragl(Plds, t, jl, g, 0);
          bL[n] = *fragl(Plds, t, jl, g, 1);
        }
#pragma unroll
        for (int m = 0; m < 2; ++m)
#pragma unroll
          for (int n = 0; n < 4; ++n) {
            f32x4 cy = aY[m][n];
            MFMA3(cy, yH[m], yL[m], bH[n], bL[n]);
            aY[m][n] = cy;
            if constexpr (MODE == 2) {
              f32x4 cz = aZ[m][n];
              MFMA3(cz, zH[m], zL[m], bH[n], bL[n]);
              aZ[m][n] = cz;
            }
          }
      }
    }
    if constexpr (MODE == 2) {
      char* oA = outA + (size_t)bz * MB;
      char* oB = outB + (size_t)bz * MB;
#pragma unroll
      for (int m = 0; m < 2; ++m) {
        const int gi0 = w * 32 + m * 16 + r0;
#pragma unroll
        for (int n = 0; n < 4; ++n) {
          const int gj = jb + n * 16 + fr;
          float base[4], vv[4];
          read_quad_g(Yb, gj, gi0, base);
#pragma unroll
          for (int j = 0; j < 4; ++j) vv[j] = 1.5f * base[j] - 0.5f * aY[m][n][j];
          write_quad_g(oA, gj, gi0, vv);
          read_quad_g(Zb, gj, gi0, base);
#pragma unroll
          for (int j = 0; j < 4; ++j) vv[j] = 1.5f * base[j] - 0.5f * aZ[m][n][j];
          write_quad_g(oB, gj, gi0, vv);
        }
      }
    } else {
      const float sq = sqrtf(nrm[bz]);
      float* Sb = Sf + (size_t)bz * 65536;
#pragma unroll
      for (int m = 0; m < 2; ++m) {
        const int gi0 = w * 32 + m * 16 + r0;
#pragma unroll
        for (int n = 0; n < 4; ++n) {
          const int gj = jb + n * 16 + fr;
          float base[4];
          read_quad_g(Yb, gj, gi0, base);
          f32x4 vv;
#pragma unroll
          for (int j = 0; j < 4; ++j)
            vv[j] = (1.5f * base[j] - 0.5f * aY[m][n][j]) * sq;
          *(f32x4*)(Sb + (size_t)gj * 256 + gi0) = vv;
        }
      }
    }
  }
}

// ---------------------------------------------------------------------------
// Per-row mean + trace(cov), from X in fmt.
__global__ __launch_bounds__(256) void meanvar(const char* __restrict__ X,
                                               float* __restrict__ mu,
                                               float* __restrict__ nrm)
{
  const int b = blockIdx.x, i = threadIdx.x;
  const char* rp0 = X + (size_t)b * 262144 + (size_t)i * 128;
  float s = 0.f, ss = 0.f;
  for (int kt = 0; kt < 8; ++kt) {
    const char* rp = rp0 + kt * 32768;
#pragma unroll
    for (int sl = 0; sl < 4; ++sl) {
      bf16x8 h8 = *(const bf16x8*)(rp + ((sl ^ (i & 7)) << 4));
      bf16x8 l8 = *(const bf16x8*)(rp + (((sl + 4) ^ (i & 7)) << 4));
#pragma unroll
      for (int e = 0; e < 8; ++e) {
        const float v = bf16v(h8[e]) + bf16v(l8[e]);
        s += v; ss += v * v;
      }
    }
  }
  const float m = s * (1.f / 256.f);
  mu[b * 256 + i] = m;
  __shared__ float red[256];
  red[i] = ss * (1.f / 256.f) - m * m;
  __syncthreads();
  for (int o = 128; o > 0; o >>= 1) {
    if (i < o) red[i] += red[i + o];
    __syncthreads();
  }
  if (i == 0) nrm[b] = red[0];
}

// ---------------------------------------------------------------------------
// Heads: out[b,v] = dot(S_b, W2_v) + bias.
__global__ __launch_bounds__(256) void head2(
    const float* __restrict__ Sf, const float* __restrict__ W2,
    const float* __restrict__ b_type, const float* __restrict__ b_flag,
    float* __restrict__ out)
{
  const int b = blockIdx.x, v = blockIdx.y, tid = threadIdx.x;
  const float4* s4 = (const float4*)(Sf + (size_t)b * 65536);
  const float4* w4 = (const float4*)(W2 + (size_t)v * 65536);
  float acc = 0.f;
  for (int i = tid; i < 16384; i += 256) {
    const float4 a = s4[i], c = w4[i];
    acc += a.x * c.x + a.y * c.y + a.z * c.z + a.w * c.w;
  }
  __shared__ float red[256];
  red[tid] = acc;
  __syncthreads();
  for (int o = 128; o > 0; o >>= 1) {
    if (tid < o) red[tid] += red[tid + o];
    __syncthreads();
  }
  if (tid == 0) {
    if (v < 4) out[b * 4 + v] = red[0] + b_type[v];
    else       out[256 + b] = red[0] + b_flag[0];
  }
}

// ---------------------------------------------------------------------------
extern "C" void kernel_launch(void* const* d_in, const int* in_sizes, int n_in,
                              void* d_out, int out_size, void* d_ws, size_t ws_size,
                              hipStream_t stream)
{
  const float* features = (const float*)d_in[0];
  const float* w_bn     = (const float*)d_in[1];
  const float* b_bn     = (const float*)d_in[2];
  const float* w_type   = (const float*)d_in[3];
  const float* b_type   = (const float*)d_in[4];
  const float* w_flag   = (const float*)d_in[5];
  const float* b_flag   = (const float*)d_in[6];
  float* out = (float*)d_out;

  char* W = (char*)d_ws;
  const size_t PB = 16777216;
  char* P0 = W;           char* P1 = W + PB;     char* P2 = W + 2 * PB;
  char* P3 = W + 3 * PB;  char* P4 = W + 4 * PB;
  char* Wf = W + 5 * PB;                          // 2 MB
  float* mu = (float*)(W + 5 * PB + 2097152);
  float* nrm = mu + 64 * 256;
  char* Ft = W + 5 * PB + 4194304;                // 128 MB (full batch)
  float* W2 = (float*)(Ft + 64ull * 2097152);     // 1.31 MB
  float* Sf = (float*)P4;                         // final S fp32 (P4 dead)

  // prep: transpose F + cvt_w + build_w2, one dispatch
  prep_k<<<dim3(4480), dim3(256), 0, stream>>>(features, w_bn, w_type, w_flag,
                                               Ft, Wf, W2);
  // conv
  conv3_k<<<dim3(4, 2, 64), dim3(256), 0, stream>>>(Wf, Ft, P0, b_bn);
  meanvar<<<dim3(64), dim3(256), 0, stream>>>(P0, mu, nrm);

  const dim3 cg(256), cb(512);
  // cov: An(P1), Z0(P2)
  col_k<0><<<cg, cb, 0, stream>>>(P0, P0, nullptr, nullptr, P1, P2, mu, nrm, nullptr);
  // Y0(P3) = 1.5An - 0.5 An^2
  col_k<1><<<cg, cb, 0, stream>>>(P1, P1, nullptr, nullptr, P3, nullptr, nullptr, nullptr, nullptr);
  // it1: Z=P2, Y=P3 -> Yn P0, Zn P4
  col_k<2><<<cg, cb, 0, stream>>>(P2, P3, P3, P2, P0, P4, nullptr, nullptr, nullptr);
  // it2: Z=P4, Y=P0 -> Yn P1, Zn P2
  col_k<2><<<cg, cb, 0, stream>>>(P4, P0, P0, P4, P1, P2, nullptr, nullptr, nullptr);
  // it3: Z=P2, Y=P1 -> Yn P3, Zn P0
  col_k<2><<<cg, cb, 0, stream>>>(P2, P1, P1, P2, P3, P0, nullptr, nullptr, nullptr);
  // fin: Z=P0, Y=P3 -> Sf
  col_k<3><<<cg, cb, 0, stream>>>(P0, P3, P3, nullptr, nullptr, nullptr, nullptr, nrm, Sf);

  head2<<<dim3(64, 5), dim3(256), 0, stream>>>(Sf, W2, b_type, b_flag, out);
  (void)in_sizes; (void)n_in; (void)out_size; (void)ws_size;
}

// Round 8
// 285.369 us; speedup vs baseline: 1.2471x; 1.2079x over previous
//
#include <hip/hip_runtime.h>
#include <math.h>

// ---------------------------------------------------------------------------
// HPFNetCovPool round 8.
// fmt storage: [batch][kt=k/32][row(256)][128B]; 128B = 8x16B slots,
// slot_log = plane*4 + ((k&31)>>3), stored at slot_log ^ (row&7).
// conv4_k: transpose FUSED into conv. F read once from HBM, coalesced; the
// ch<->px transpose goes through a small padded LDS fp32 tile; weights (L2)
// are read fragment-direct with 2-deep register prefetch. One raw s_barrier
// per kt (lgkmcnt(0) only -- vmem stays in flight across barriers).
// NS chain (col_k), meanvar, heads unchanged.
// ---------------------------------------------------------------------------

typedef __attribute__((ext_vector_type(8))) short bf16x8;
typedef __attribute__((ext_vector_type(4))) float f32x4;
typedef __attribute__((ext_vector_type(4))) unsigned u32x4;
typedef __attribute__((ext_vector_type(2))) unsigned u32x2;

__device__ __forceinline__ unsigned fbits(float f) { union { float f; unsigned u; } x; x.f = f; return x.u; }
__device__ __forceinline__ float bitsf(unsigned u) { union { float f; unsigned u; } x; x.u = u; return x.f; }
__device__ __forceinline__ float bf16v(short h) { return bitsf(((unsigned)(unsigned short)h) << 16); }

__device__ __forceinline__ unsigned pack_h(float a, float b) {
  return (fbits(a) >> 16) | (fbits(b) & 0xFFFF0000u);
}
__device__ __forceinline__ unsigned pack_l(float a, float b) {
  float la = a - bitsf(fbits(a) & 0xFFFF0000u);
  float lb = b - bitsf(fbits(b) & 0xFFFF0000u);
  return (fbits(la) >> 16) | (fbits(lb) & 0xFFFF0000u);
}

__device__ __forceinline__ const bf16x8* fragp(const char* M, int kt, int row,
                                               int g, int pl) {
  return (const bf16x8*)(M + (size_t)kt * 32768 + (size_t)row * 128 +
                         ((((pl << 2) + g) ^ (row & 7)) << 4));
}
__device__ __forceinline__ const bf16x8* fragl(const char* L, int kt, int row,
                                               int g, int pl) {
  return (const bf16x8*)(L + kt * 8192 + row * 128 +
                         ((((pl << 2) + g) ^ (row & 7)) << 4));
}

__device__ __forceinline__ void write_quad_g(char* M, int row, int k0,
                                             const float* v) {
  char* rp = M + (size_t)(k0 >> 5) * 32768 + (size_t)row * 128;
  const int s = (k0 & 31) >> 3, bo = (k0 & 7) * 2;
  *(u32x2*)(rp + (((s) ^ (row & 7)) << 4) + bo) =
      (u32x2){pack_h(v[0], v[1]), pack_h(v[2], v[3])};
  *(u32x2*)(rp + (((s + 4) ^ (row & 7)) << 4) + bo) =
      (u32x2){pack_l(v[0], v[1]), pack_l(v[2], v[3])};
}
__device__ __forceinline__ void write_quad_l(char* L, int row, int k0,
                                             const float* v) {
  char* rp = L + (k0 >> 5) * 8192 + row * 128;
  const int s = (k0 & 31) >> 3, bo = (k0 & 7) * 2;
  *(u32x2*)(rp + (((s) ^ (row & 7)) << 4) + bo) =
      (u32x2){pack_h(v[0], v[1]), pack_h(v[2], v[3])};
  *(u32x2*)(rp + (((s + 4) ^ (row & 7)) << 4) + bo) =
      (u32x2){pack_l(v[0], v[1]), pack_l(v[2], v[3])};
}
__device__ __forceinline__ void read_quad_g(const char* M, int row, int k0,
                                            float* v) {
  const char* rp = M + (size_t)(k0 >> 5) * 32768 + (size_t)row * 128;
  const int s = (k0 & 31) >> 3, bo = (k0 & 7) * 2;
  const u32x2 hq = *(const u32x2*)(rp + (((s) ^ (row & 7)) << 4) + bo);
  const u32x2 lq = *(const u32x2*)(rp + (((s + 4) ^ (row & 7)) << 4) + bo);
  v[0] = bitsf(hq[0] << 16) + bitsf(lq[0] << 16);
  v[1] = bitsf(hq[0] & 0xFFFF0000u) + bitsf(lq[0] & 0xFFFF0000u);
  v[2] = bitsf(hq[1] << 16) + bitsf(lq[1] << 16);
  v[3] = bitsf(hq[1] & 0xFFFF0000u) + bitsf(lq[1] & 0xFFFF0000u);
}

#define MFMA3(c, aH, aL, bH, bL)                                            \
  c = __builtin_amdgcn_mfma_f32_16x16x32_bf16(aL, bH, c, 0, 0, 0);          \
  c = __builtin_amdgcn_mfma_f32_16x16x32_bf16(aH, bL, c, 0, 0, 0);          \
  c = __builtin_amdgcn_mfma_f32_16x16x32_bf16(aH, bH, c, 0, 0, 0);

// raw barrier keeping vmem in flight; lgkm(0) orders our ds ops block-wide.
#define LGKM_BAR() do { asm volatile("s_waitcnt lgkmcnt(0)" ::: "memory"); \
                        __builtin_amdgcn_s_barrier(); } while (0)

// ---------------------------------------------------------------------------
// prep: [0,64) w_bn->Wf fmt ; [64,384) build W2.
__global__ __launch_bounds__(256) void prep_k(
    const float* __restrict__ w_bn, const float* __restrict__ w_type,
    const float* __restrict__ w_flag, char* __restrict__ Wf,
    float* __restrict__ W2)
{
  const int bid = blockIdx.x;
  if (bid < 64) {
    const int kt = bid, r = threadIdx.x;
    const float* src = w_bn + (size_t)r * 2048 + kt * 32;
    char* rp = Wf + (size_t)kt * 32768 + (size_t)r * 128;
#pragma unroll
    for (int s = 0; s < 4; ++s) {
      float x[8];
#pragma unroll
      for (int e = 0; e < 8; ++e) x[e] = src[s * 8 + e];
      *(u32x4*)(rp + ((s ^ (r & 7)) << 4)) =
          (u32x4){pack_h(x[0], x[1]), pack_h(x[2], x[3]),
                  pack_h(x[4], x[5]), pack_h(x[6], x[7])};
      *(u32x4*)(rp + (((s + 4) ^ (r & 7)) << 4)) =
          (u32x4){pack_l(x[0], x[1]), pack_l(x[2], x[3]),
                  pack_l(x[4], x[5]), pack_l(x[6], x[7])};
    }
  } else {
    const int idx = bid - 64;
    const int v = idx >> 6, chunk = idx & 63;
    const float* src = (v < 4) ? (w_type + (size_t)v * 32896) : w_flag;
    const int e0 = chunk * 1024 + threadIdx.x * 4;
#pragma unroll
    for (int q = 0; q < 4; ++q) {
      const int e = e0 + q;
      const int i = e >> 8, j = e & 255;
      const int r = i < j ? i : j, c = i < j ? j : i;
      const int t = r * 256 - (r * (r - 1)) / 2 + (c - r);
      W2[(size_t)v * 65536 + e] = src[t] * (i == j ? 1.0f : 0.5f);
    }
  }
}

// ---------------------------------------------------------------------------
// conv4: X[ch][px] = Wf @ F^T + bias, transpose fused. 512 thr (8 waves 4x2),
// tile 256ch x 64px, grid (4 jb, 64 bz). F read once, coalesced.
__global__ __launch_bounds__(512) void conv4_k(
    const char* __restrict__ Wf, const float* __restrict__ F,
    char* __restrict__ X, const float* __restrict__ bias)
{
  __shared__ __align__(16) float bf32[2][64 * 36];  // [px][36-pad dwords]
  __shared__ __align__(16) char bfmt[2][8192];      // fmt B tile (64 rows)

  const int tid = threadIdx.x, lane = tid & 63, w = tid >> 6;
  const int wr = w >> 1, wc = w & 1, fr = lane & 15, g = lane >> 4;
  const int jb = blockIdx.x * 64, bz = blockIdx.y;
  const float* Fb = F + (size_t)bz * 524288;

  const int blc = tid >> 4, blpx = (tid & 15) * 4;       // bload: row c, 4 px
  const int pkpx = tid >> 3, pkq = tid & 3, pkpl = (tid >> 2) & 1;  // pack

  f32x4 acc[4][2] = {};
  bf16x8 pa0[4][2], pa1[4][2];
  float4 bl0, bl1;

  auto bload = [&](int t, float4& r) {
    r = *(const float4*)(Fb + ((size_t)t * 32 + blc) * 256 + jb + blpx);
  };
  auto bf32w = [&](int buf, const float4& r) {
    float* p = &bf32[buf][0];
    p[(blpx + 0) * 36 + blc] = r.x;
    p[(blpx + 1) * 36 + blc] = r.y;
    p[(blpx + 2) * 36 + blc] = r.z;
    p[(blpx + 3) * 36 + blc] = r.w;
  };
  auto aload = [&](int t, bf16x8 (*pa)[2]) {
#pragma unroll
    for (int m = 0; m < 4; ++m) {
      const int r = wr * 64 + m * 16 + fr;
#pragma unroll
      for (int pl = 0; pl < 2; ++pl) pa[m][pl] = *fragp(Wf, t, r, g, pl);
    }
  };
  auto pack = [&](int buf) {
    const float* p = &bf32[buf][pkpx * 36 + pkq * 8];
    const f32x4 a = *(const f32x4*)(p);
    const f32x4 b = *(const f32x4*)(p + 4);
    u32x4 outv;
    if (pkpl == 0)
      outv = (u32x4){pack_h(a[0], a[1]), pack_h(a[2], a[3]),
                     pack_h(b[0], b[1]), pack_h(b[2], b[3])};
    else
      outv = (u32x4){pack_l(a[0], a[1]), pack_l(a[2], a[3]),
                     pack_l(b[0], b[1]), pack_l(b[2], b[3])};
    const int slot = ((pkpl << 2) + pkq) ^ (pkpx & 7);
    *(u32x4*)(&bfmt[buf][pkpx * 128 + slot * 16]) = outv;
  };
  auto gemmstep = [&](int buf, bf16x8 (*pa)[2]) {
    bf16x8 bH[2], bL[2];
#pragma unroll
    for (int n = 0; n < 2; ++n) {
      const int r = wc * 32 + n * 16 + fr;
      const char* rp = &bfmt[buf][r * 128];
      bH[n] = *(const bf16x8*)(rp + ((g ^ (r & 7)) << 4));
      bL[n] = *(const bf16x8*)(rp + (((g + 4) ^ (r & 7)) << 4));
    }
#pragma unroll
    for (int m = 0; m < 4; ++m)
#pragma unroll
      for (int n = 0; n < 2; ++n) {
        f32x4 c = acc[m][n];
        MFMA3(c, pa[m][0], pa[m][1], bH[n], bL[n]);
        acc[m][n] = c;
      }
  };

  // prologue
  bload(0, bl0);
  bf32w(0, bl0);
  bload(1, bl1);
  aload(0, pa0);
  LGKM_BAR();              // Bf32[0] visible
  bf32w(1, bl1);
  pack(0);
  aload(1, pa1);
  bload(2, bl0);
  LGKM_BAR();              // Bfmt[0], Bf32[1] visible

  for (int t2 = 0; t2 < 64; t2 += 2) {
    // t = t2 (buf 0)
    gemmstep(0, pa0);
    if (t2 + 1 < 64) pack(1);                       // Bf32[1] -> Bfmt[1]
    if (t2 + 2 < 64) { bf32w(0, bl0); aload(t2 + 2, pa0); }
    if (t2 + 3 < 64) bload(t2 + 3, bl1);
    LGKM_BAR();
    // t = t2+1 (buf 1)
    gemmstep(1, pa1);
    if (t2 + 2 < 64) pack(0);                       // Bf32[0] -> Bfmt[0]
    if (t2 + 3 < 64) { bf32w(1, bl1); aload(t2 + 3, pa1); }
    if (t2 + 4 < 64) bload(t2 + 4, bl0);
    LGKM_BAR();
  }

  // epilogue: X fmt row = channel gi, k = pixel gj
  char* Xb = X + (size_t)bz * 262144;
#pragma unroll
  for (int m = 0; m < 4; ++m) {
    const int gi0 = wr * 64 + m * 16 + g * 4;
#pragma unroll
    for (int n = 0; n < 2; ++n) {
      const int gj = jb + wc * 32 + n * 16 + fr;
      const int ktj = gj >> 5, sj = (gj & 31) >> 3, bo = (gj & 7) * 2;
#pragma unroll
      for (int j = 0; j < 4; ++j) {
        const int gi = gi0 + j;
        char* rp = Xb + (size_t)ktj * 32768 + (size_t)gi * 128;
        const float v = acc[m][n][j] + bias[gi];
        const unsigned u = fbits(v);
        *(short*)(rp + ((sj ^ (gi & 7)) << 4) + bo) = (short)(u >> 16);
        *(short*)(rp + (((sj + 4) ^ (gi & 7)) << 4) + bo) =
            (short)(fbits(v - bitsf(u & 0xFFFF0000u)) >> 16);
      }
    }
  }
}

// ---------------------------------------------------------------------------
// Column-fused NS kernel (unchanged). grid 256 x 512 thr.
template <int MODE>
__global__ __launch_bounds__(512) void col_k(
    const char* __restrict__ A1, const char* __restrict__ Bsrc,
    const char* __restrict__ Ys, const char* __restrict__ Zs,
    char* __restrict__ outA, char* __restrict__ outB,
    const float* __restrict__ mu, const float* __restrict__ nrm,
    float* __restrict__ Sf)
{
  __shared__ __align__(16) char Plds[65536];
  const int tid = threadIdx.x, lane = tid & 63, w = tid >> 6;
  const int fr = lane & 15, g = lane >> 4;
  const int blk = blockIdx.x;
  const int bz = (blk & 7) * 8 + ((blk >> 3) & 7);
  const int jb = (blk >> 6) * 64;
  const size_t MB = 262144;
  const char* Ab = A1 + (size_t)bz * MB;
  const char* Bb = Bsrc + (size_t)bz * MB;
  const int r0 = g * 4;

  f32x4 acc[2][4] = {};
  {
    bf16x8 pa[2][2][2], pb[2][4][2];
#pragma unroll
    for (int par = 0; par < 2; ++par) {
#pragma unroll
      for (int m = 0; m < 2; ++m) {
        const int r = w * 32 + m * 16 + fr;
#pragma unroll
        for (int pl = 0; pl < 2; ++pl) pa[par][m][pl] = *fragp(Ab, par, r, g, pl);
      }
#pragma unroll
      for (int n = 0; n < 4; ++n) {
        const int r = jb + n * 16 + fr;
#pragma unroll
        for (int pl = 0; pl < 2; ++pl) pb[par][n][pl] = *fragp(Bb, par, r, g, pl);
      }
    }
    for (int t2 = 0; t2 < 8; t2 += 2) {
#pragma unroll
      for (int par = 0; par < 2; ++par) {
        const int t = t2 + par;
        bf16x8 aH[2], aL[2], bH[4], bL[4];
#pragma unroll
        for (int m = 0; m < 2; ++m) { aH[m] = pa[par][m][0]; aL[m] = pa[par][m][1]; }
#pragma unroll
        for (int n = 0; n < 4; ++n) { bH[n] = pb[par][n][0]; bL[n] = pb[par][n][1]; }
        if (t + 2 < 8) {
#pragma unroll
          for (int m = 0; m < 2; ++m) {
            const int r = w * 32 + m * 16 + fr;
#pragma unroll
            for (int pl = 0; pl < 2; ++pl)
              pa[par][m][pl] = *fragp(Ab, t + 2, r, g, pl);
          }
#pragma unroll
          for (int n = 0; n < 4; ++n) {
            const int r = jb + n * 16 + fr;
#pragma unroll
            for (int pl = 0; pl < 2; ++pl)
              pb[par][n][pl] = *fragp(Bb, t + 2, r, g, pl);
          }
        }
#pragma unroll
        for (int m = 0; m < 2; ++m)
#pragma unroll
          for (int n = 0; n < 4; ++n) {
            f32x4 c = acc[m][n];
            MFMA3(c, aH[m], aL[m], bH[n], bL[n]);
            acc[m][n] = c;
          }
      }
    }
  }

  if constexpr (MODE == 0) {
    const float rn = 1.0f / nrm[bz];
    const float* mub = mu + bz * 256;
    char* oA = outA + (size_t)bz * MB;
    char* oB = outB + (size_t)bz * MB;
#pragma unroll
    for (int m = 0; m < 2; ++m) {
      const int gi0 = w * 32 + m * 16 + r0;
#pragma unroll
      for (int n = 0; n < 4; ++n) {
        const int gj = jb + n * 16 + fr;
        float vv[4], zz[4];
#pragma unroll
        for (int j = 0; j < 4; ++j) {
          const float v =
              (acc[m][n][j] * (1.f / 256.f) - mub[gi0 + j] * mub[gj]) * rn;
          vv[j] = v;
          zz[j] = (gi0 + j == gj ? 1.5f : 0.f) - 0.5f * v;
        }
        write_quad_g(oA, gj, gi0, vv);
        write_quad_g(oB, gj, gi0, zz);
      }
    }
  } else if constexpr (MODE == 1) {
    char* oA = outA + (size_t)bz * MB;
#pragma unroll
    for (int m = 0; m < 2; ++m) {
      const int gi0 = w * 32 + m * 16 + r0;
#pragma unroll
      for (int n = 0; n < 4; ++n) {
        const int gj = jb + n * 16 + fr;
        float av[4], vv[4];
        read_quad_g(Bb, gj, gi0, av);
#pragma unroll
        for (int j = 0; j < 4; ++j) vv[j] = 1.5f * av[j] - 0.5f * acc[m][n][j];
        write_quad_g(oA, gj, gi0, vv);
      }
    }
  } else {
#pragma unroll
    for (int m = 0; m < 2; ++m) {
      const int gi0 = w * 32 + m * 16 + r0;
#pragma unroll
      for (int n = 0; n < 4; ++n) {
        const int jl = n * 16 + fr;
        float vv[4] = {acc[m][n][0], acc[m][n][1], acc[m][n][2], acc[m][n][3]};
        write_quad_l(Plds, jl, gi0, vv);
      }
    }
    const char* Yb = Ys + (size_t)bz * MB;
    const char* Zb = (MODE == 2) ? (Zs + (size_t)bz * MB) : nullptr;
    bf16x8 py[2][2][2], pz[2][2][2];
#pragma unroll
    for (int par = 0; par < 2; ++par)
#pragma unroll
      for (int m = 0; m < 2; ++m) {
        const int r = w * 32 + m * 16 + fr;
#pragma unroll
        for (int pl = 0; pl < 2; ++pl) {
          py[par][m][pl] = *fragp(Yb, par, r, g, pl);
          if constexpr (MODE == 2) pz[par][m][pl] = *fragp(Zb, par, r, g, pl);
        }
      }
    __syncthreads();

    f32x4 aY[2][4] = {}, aZ[2][4] = {};
    for (int t2 = 0; t2 < 8; t2 += 2) {
#pragma unroll
      for (int par = 0; par < 2; ++par) {
        const int t = t2 + par;
        bf16x8 yH[2], yL[2], zH[2], zL[2];
#pragma unroll
        for (int m = 0; m < 2; ++m) {
          yH[m] = py[par][m][0]; yL[m] = py[par][m][1];
          if constexpr (MODE == 2) { zH[m] = pz[par][m][0]; zL[m] = pz[par][m][1]; }
        }
        if (t + 2 < 8) {
#pragma unroll
          for (int m = 0; m < 2; ++m) {
            const int r = w * 32 + m * 16 + fr;
#pragma unroll
            for (int pl = 0; pl < 2; ++pl) {
              py[par][m][pl] = *fragp(Yb, t + 2, r, g, pl);
              if constexpr (MODE == 2) pz[par][m][pl] = *fragp(Zb, t + 2, r, g, pl);
            }
          }
        }
        bf16x8 bH[4], bL[4];
#pragma unroll
        for (int n = 0; n < 4; ++n) {
          const int jl = n * 16 + fr;
          bH[n] = *fragl(Plds, t, jl, g, 0);
          bL[n] = *fragl(Plds, t, jl, g, 1);
        }
#pragma unroll
        for (int m = 0; m < 2; ++m)
#pragma unroll
          for (int n = 0; n < 4; ++n) {
            f32x4 cy = aY[m][n];
            MFMA3(cy, yH[m], yL[m], bH[n], bL[n]);
            aY[m][n] = cy;
            if constexpr (MODE == 2) {
              f32x4 cz = aZ[m][n];
              MFMA3(cz, zH[m], zL[m], bH[n], bL[n]);
              aZ[m][n] = cz;
            }
          }
      }
    }
    if constexpr (MODE == 2) {
      char* oA = outA + (size_t)bz * MB;
      char* oB = outB + (size_t)bz * MB;
#pragma unroll
      for (int m = 0; m < 2; ++m) {
        const int gi0 = w * 32 + m * 16 + r0;
#pragma unroll
        for (int n = 0; n < 4; ++n) {
          const int gj = jb + n * 16 + fr;
          float base[4], vv[4];
          read_quad_g(Yb, gj, gi0, base);
#pragma unroll
          for (int j = 0; j < 4; ++j) vv[j] = 1.5f * base[j] - 0.5f * aY[m][n][j];
          write_quad_g(oA, gj, gi0, vv);
          read_quad_g(Zb, gj, gi0, base);
#pragma unroll
          for (int j = 0; j < 4; ++j) vv[j] = 1.5f * base[j] - 0.5f * aZ[m][n][j];
          write_quad_g(oB, gj, gi0, vv);
        }
      }
    } else {
      const float sq = sqrtf(nrm[bz]);
      float* Sb = Sf + (size_t)bz * 65536;
#pragma unroll
      for (int m = 0; m < 2; ++m) {
        const int gi0 = w * 32 + m * 16 + r0;
#pragma unroll
        for (int n = 0; n < 4; ++n) {
          const int gj = jb + n * 16 + fr;
          float base[4];
          read_quad_g(Yb, gj, gi0, base);
          f32x4 vv;
#pragma unroll
          for (int j = 0; j < 4; ++j)
            vv[j] = (1.5f * base[j] - 0.5f * aY[m][n][j]) * sq;
          *(f32x4*)(Sb + (size_t)gj * 256 + gi0) = vv;
        }
      }
    }
  }
}

// ---------------------------------------------------------------------------
// Per-row mean + trace(cov), from X in fmt.
__global__ __launch_bounds__(256) void meanvar(const char* __restrict__ X,
                                               float* __restrict__ mu,
                                               float* __restrict__ nrm)
{
  const int b = blockIdx.x, i = threadIdx.x;
  const char* rp0 = X + (size_t)b * 262144 + (size_t)i * 128;
  float s = 0.f, ss = 0.f;
  for (int kt = 0; kt < 8; ++kt) {
    const char* rp = rp0 + kt * 32768;
#pragma unroll
    for (int sl = 0; sl < 4; ++sl) {
      bf16x8 h8 = *(const bf16x8*)(rp + ((sl ^ (i & 7)) << 4));
      bf16x8 l8 = *(const bf16x8*)(rp + (((sl + 4) ^ (i & 7)) << 4));
#pragma unroll
      for (int e = 0; e < 8; ++e) {
        const float v = bf16v(h8[e]) + bf16v(l8[e]);
        s += v; ss += v * v;
      }
    }
  }
  const float m = s * (1.f / 256.f);
  mu[b * 256 + i] = m;
  __shared__ float red[256];
  red[i] = ss * (1.f / 256.f) - m * m;
  __syncthreads();
  for (int o = 128; o > 0; o >>= 1) {
    if (i < o) red[i] += red[i + o];
    __syncthreads();
  }
  if (i == 0) nrm[b] = red[0];
}

// ---------------------------------------------------------------------------
// Heads: out[b,v] = dot(S_b, W2_v) + bias.
__global__ __launch_bounds__(256) void head2(
    const float* __restrict__ Sf, const float* __restrict__ W2,
    const float* __restrict__ b_type, const float* __restrict__ b_flag,
    float* __restrict__ out)
{
  const int b = blockIdx.x, v = blockIdx.y, tid = threadIdx.x;
  const float4* s4 = (const float4*)(Sf + (size_t)b * 65536);
  const float4* w4 = (const float4*)(W2 + (size_t)v * 65536);
  float acc = 0.f;
  for (int i = tid; i < 16384; i += 256) {
    const float4 a = s4[i], c = w4[i];
    acc += a.x * c.x + a.y * c.y + a.z * c.z + a.w * c.w;
  }
  __shared__ float red[256];
  red[tid] = acc;
  __syncthreads();
  for (int o = 128; o > 0; o >>= 1) {
    if (tid < o) red[tid] += red[tid + o];
    __syncthreads();
  }
  if (tid == 0) {
    if (v < 4) out[b * 4 + v] = red[0] + b_type[v];
    else       out[256 + b] = red[0] + b_flag[0];
  }
}

// ---------------------------------------------------------------------------
extern "C" void kernel_launch(void* const* d_in, const int* in_sizes, int n_in,
                              void* d_out, int out_size, void* d_ws, size_t ws_size,
                              hipStream_t stream)
{
  const float* features = (const float*)d_in[0];
  const float* w_bn     = (const float*)d_in[1];
  const float* b_bn     = (const float*)d_in[2];
  const float* w_type   = (const float*)d_in[3];
  const float* b_type   = (const float*)d_in[4];
  const float* w_flag   = (const float*)d_in[5];
  const float* b_flag   = (const float*)d_in[6];
  float* out = (float*)d_out;

  char* W = (char*)d_ws;
  const size_t PB = 16777216;
  char* P0 = W;           char* P1 = W + PB;     char* P2 = W + 2 * PB;
  char* P3 = W + 3 * PB;  char* P4 = W + 4 * PB;
  char* Wf = W + 5 * PB;                          // 2 MB
  float* W2 = (float*)(W + 5 * PB + 2097152);     // 1.31 MB
  float* mu = (float*)(W + 5 * PB + 4194304);
  float* nrm = mu + 64 * 256;
  float* Sf = (float*)P4;                         // final S fp32 (P4 dead)

  prep_k<<<dim3(384), dim3(256), 0, stream>>>(w_bn, w_type, w_flag, Wf, W2);
  conv4_k<<<dim3(4, 64), dim3(512), 0, stream>>>(Wf, features, P0, b_bn);
  meanvar<<<dim3(64), dim3(256), 0, stream>>>(P0, mu, nrm);

  const dim3 cg(256), cb(512);
  // cov: An(P1), Z0(P2)
  col_k<0><<<cg, cb, 0, stream>>>(P0, P0, nullptr, nullptr, P1, P2, mu, nrm, nullptr);
  // Y0(P3) = 1.5An - 0.5 An^2
  col_k<1><<<cg, cb, 0, stream>>>(P1, P1, nullptr, nullptr, P3, nullptr, nullptr, nullptr, nullptr);
  // it1: Z=P2, Y=P3 -> Yn P0, Zn P4
  col_k<2><<<cg, cb, 0, stream>>>(P2, P3, P3, P2, P0, P4, nullptr, nullptr, nullptr);
  // it2: Z=P4, Y=P0 -> Yn P1, Zn P2
  col_k<2><<<cg, cb, 0, stream>>>(P4, P0, P0, P4, P1, P2, nullptr, nullptr, nullptr);
  // it3: Z=P2, Y=P1 -> Yn P3, Zn P0
  col_k<2><<<cg, cb, 0, stream>>>(P2, P1, P1, P2, P3, P0, nullptr, nullptr, nullptr);
  // fin: Z=P0, Y=P3 -> Sf
  col_k<3><<<cg, cb, 0, stream>>>(P0, P3, P3, nullptr, nullptr, nullptr, nullptr, nrm, Sf);

  head2<<<dim3(64, 5), dim3(256), 0, stream>>>(Sf, W2, b_type, b_flag, out);
  (void)in_sizes; (void)n_in; (void)out_size; (void)ws_size;
}